// Round 1
// baseline (70.155 us; speedup 1.0000x reference)
//
#include <hip/hip_runtime.h>
#include <stdint.h>

// CandidateFinder: binary-quantize (x>0), exact match on two 32-bit dim
// groups (union), gather first <=64 matching key indices per query, pad -1.
//
// L=2048, D=64 (= 2 groups x 32 bits), K=64. wave=64 lanes <-> 64 dims, so
// __ballot(x>0) packs one row's sign bits into exactly the two uint32
// signatures we need.

#define LSEQ 2048
#define DDIM 64
#define KMAX 64

// Kernel 1: one wave per key row -> pack 64 sign bits into uint2 signature.
__global__ __launch_bounds__(256) void keysig_kernel(
    const float* __restrict__ key, uint2* __restrict__ ksig, int nrows) {
    int row  = (int)((blockIdx.x * blockDim.x + threadIdx.x) >> 6);  // wave id
    int lane = threadIdx.x & 63;
    if (row >= nrows) return;                       // wave-uniform branch
    float v = key[(size_t)row * DDIM + lane];       // coalesced 256B/wave
    unsigned long long m = __ballot(v > 0.0f);      // bit i = lane i sign
    if (lane == 0) ksig[row] = make_uint2((unsigned)m, (unsigned)(m >> 32));
}

// Kernel 2: one wave per query. Compute query signature via ballot, then
// scan the batch's 2048 key signatures in 32 chunks of 64 (one key/lane).
// Matches are emitted in ascending key-index order via ballot+popcount
// prefix, which reproduces the reference's sort-then-truncate exactly.
__global__ __launch_bounds__(256) void match_kernel(
    const float* __restrict__ query, const uint2* __restrict__ ksig,
    int* __restrict__ out, int nq) {
    int qid  = (int)((blockIdx.x * blockDim.x + threadIdx.x) >> 6);  // wave id
    int lane = threadIdx.x & 63;
    if (qid >= nq) return;                          // wave-uniform branch
    int b = qid >> 11;                              // qid / LSEQ

    float v = query[(size_t)qid * DDIM + lane];     // coalesced 256B/wave
    unsigned long long qm = __ballot(v > 0.0f);
    unsigned q1 = (unsigned)qm, q2 = (unsigned)(qm >> 32);

    const uint2* ks = ksig + (size_t)b * LSEQ;
    int* obase = out + (size_t)qid * KMAX;
    unsigned long long below = (1ull << lane) - 1ull;  // lanes strictly below

    int cnt = 0;
    for (int c = 0; c < LSEQ / 64; ++c) {
        uint2 kv = ks[c * 64 + lane];               // coalesced 512B/wave, L2-hot
        bool m = (kv.x == q1) || (kv.y == q2);
        unsigned long long mask = __ballot(m);
        if (mask) {
            if (m) {
                int pos = cnt + __popcll(mask & below);
                if (pos < KMAX) obase[pos] = c * 64 + lane;
            }
            cnt += __popcll(mask);                  // wave-uniform
            if (cnt >= KMAX) break;                 // all K slots filled
        }
    }
    // pad remaining slots with -1 (lane < 64 == KMAX; disjoint from matches)
    if (lane >= cnt) obase[lane] = -1;
}

// Fallback if ws_size < B*L*8 bytes: fused kernel, key sigs staged in LDS.
// One block = 64 queries of one batch; 4 waves cooperatively build all 2048
// key signatures for the batch in LDS (16 KB), then each wave scans for its
// 16 queries.
__global__ __launch_bounds__(256) void fused_kernel(
    const float* __restrict__ query, const float* __restrict__ key,
    int* __restrict__ out) {
    __shared__ uint2 ksig[LSEQ];                    // 16 KB
    const int blocksPerBatch = LSEQ / 64;           // 32
    int b    = blockIdx.x / blocksPerBatch;
    int qblk = blockIdx.x % blocksPerBatch;
    int lane = threadIdx.x & 63;
    int wave = threadIdx.x >> 6;

    const float* kb = key + (size_t)b * LSEQ * DDIM;
    for (int row = wave; row < LSEQ; row += 4) {
        float v = kb[(size_t)row * DDIM + lane];
        unsigned long long m = __ballot(v > 0.0f);
        if (lane == 0) ksig[row] = make_uint2((unsigned)m, (unsigned)(m >> 32));
    }
    __syncthreads();

    const float* qb = query + (size_t)b * LSEQ * DDIM;
    unsigned long long below = (1ull << lane) - 1ull;
    for (int t = 0; t < 16; ++t) {
        int qi = qblk * 64 + wave * 16 + t;
        float v = qb[(size_t)qi * DDIM + lane];
        unsigned long long qm = __ballot(v > 0.0f);
        unsigned q1 = (unsigned)qm, q2 = (unsigned)(qm >> 32);
        int* obase = out + ((size_t)b * LSEQ + qi) * KMAX;
        int cnt = 0;
        for (int c = 0; c < LSEQ / 64; ++c) {
            uint2 kv = ksig[c * 64 + lane];         // 8B/lane, 2-way alias: free
            bool m = (kv.x == q1) || (kv.y == q2);
            unsigned long long mask = __ballot(m);
            if (mask) {
                if (m) {
                    int pos = cnt + __popcll(mask & below);
                    if (pos < KMAX) obase[pos] = c * 64 + lane;
                }
                cnt += __popcll(mask);
                if (cnt >= KMAX) break;
            }
        }
        if (lane >= cnt) obase[lane] = -1;
    }
}

extern "C" void kernel_launch(void* const* d_in, const int* in_sizes, int n_in,
                              void* d_out, int out_size, void* d_ws, size_t ws_size,
                              hipStream_t stream) {
    const float* q = (const float*)d_in[0];
    const float* k = (const float*)d_in[1];
    // d_in[2] = head_idx, unused (inputs are already per-head)
    int* out = (int*)d_out;

    int total = in_sizes[0];             // B * L * D
    int B = total / (LSEQ * DDIM);       // = 4
    int nrows = B * LSEQ;                // key rows == queries == 8192

    size_t need = (size_t)nrows * sizeof(uint2);   // 64 KB
    if (ws_size >= need) {
        uint2* ksig = (uint2*)d_ws;
        int threads = nrows * 64;        // one wave per row
        keysig_kernel<<<(threads + 255) / 256, 256, 0, stream>>>(k, ksig, nrows);
        match_kernel<<<(threads + 255) / 256, 256, 0, stream>>>(q, ksig, out, nrows);
    } else {
        fused_kernel<<<B * (LSEQ / 64), 256, 0, stream>>>(q, k, out);
    }
}